// Round 2
// baseline (399.434 us; speedup 1.0000x reference)
//
#include <hip/hip_runtime.h>
#include <hip/hip_cooperative_groups.h>
#include <math.h>

namespace cg = cooperative_groups;

// Problem constants (fixed by setup_inputs): N=65536 rows, D=512, out = 1 float.
#define NROWS 65536
#define DIM   512

typedef float f4 __attribute__((ext_vector_type(4)));

__device__ __forceinline__ unsigned bucket_of(float r) {
    // r in [0,1); mult by 2^16 is exact (exponent shift) -> monotone bucketing.
    unsigned b = (unsigned)(r * 65536.0f);
    return b > 65535u ? 65535u : b;
}

// --- per-row cosine sims -> e2/e3 (histogram moved to k_tail) ---------------
// 4 rows per wave: b2/b3 fragments + norms live in registers once per wave,
// 8 outstanding 16B x-loads per lane. Arithmetic trees identical to the
// verified version (bitwise-same e2/e3).
__global__ __launch_bounds__(256) void k_rows(
    const float* __restrict__ x, const float* __restrict__ b2,
    const float* __restrict__ b3,
    float* __restrict__ e2, float* __restrict__ e3)
{
    const int wv   = (int)((blockIdx.x * 256u + threadIdx.x) >> 6);
    const int lane = threadIdx.x & 63;
    const int row0 = wv << 2;  // 4 rows per wave

    const f4* b2v = (const f4*)b2;
    const f4* b3v = (const f4*)b3;
    const f4 u0 = b2v[lane], u1 = b2v[lane + 64];
    const f4 w0 = b3v[lane], w1 = b3v[lane + 64];

    // ||b2||, ||b3|| once per wave
    float sb2 = 0.f, sb3 = 0.f;
    sb2 += u0.x * u0.x + u0.y * u0.y + u0.z * u0.z + u0.w * u0.w;
    sb2 += u1.x * u1.x + u1.y * u1.y + u1.z * u1.z + u1.w * u1.w;
    sb3 += w0.x * w0.x + w0.y * w0.y + w0.z * w0.z + w0.w * w0.w;
    sb3 += w1.x * w1.x + w1.y * w1.y + w1.z * w1.z + w1.w * w1.w;
#pragma unroll
    for (int off = 32; off > 0; off >>= 1) {
        sb2 += __shfl_xor(sb2, off);
        sb3 += __shfl_xor(sb3, off);
    }
    const float nb2 = sqrtf(sb2);
    const float nb3 = sqrtf(sb3);

    // Preload all 8 x float4s (4 rows x 2) -> 8 outstanding non-temporal loads.
    const f4* xr = (const f4*)(x + (size_t)row0 * DIM);
    f4 xv[4][2];
#pragma unroll
    for (int r = 0; r < 4; ++r) {
#pragma unroll
        for (int k = 0; k < 2; ++k)
            xv[r][k] = __builtin_nontemporal_load(&xr[r * 128 + lane + (k << 6)]);
    }

#pragma unroll
    for (int r = 0; r < 4; ++r) {
        float dot2 = 0.f, dot3 = 0.f, ss = 0.f;
        dot2 += xv[r][0].x * u0.x + xv[r][0].y * u0.y + xv[r][0].z * u0.z + xv[r][0].w * u0.w;
        dot2 += xv[r][1].x * u1.x + xv[r][1].y * u1.y + xv[r][1].z * u1.z + xv[r][1].w * u1.w;
        dot3 += xv[r][0].x * w0.x + xv[r][0].y * w0.y + xv[r][0].z * w0.z + xv[r][0].w * w0.w;
        dot3 += xv[r][1].x * w1.x + xv[r][1].y * w1.y + xv[r][1].z * w1.z + xv[r][1].w * w1.w;
        ss   += xv[r][0].x * xv[r][0].x + xv[r][0].y * xv[r][0].y + xv[r][0].z * xv[r][0].z + xv[r][0].w * xv[r][0].w;
        ss   += xv[r][1].x * xv[r][1].x + xv[r][1].y * xv[r][1].y + xv[r][1].z * xv[r][1].z + xv[r][1].w * xv[r][1].w;
#pragma unroll
        for (int off = 32; off > 0; off >>= 1) {
            dot2 += __shfl_xor(dot2, off);
            dot3 += __shfl_xor(dot3, off);
            ss   += __shfl_xor(ss, off);
        }
        if (lane == 0) {
            const float nx = sqrtf(ss);
            const float s2 = dot2 / fmaxf(nx * nb2, 1e-8f);
            const float s3 = dot3 / fmaxf(nx * nb3, 1e-8f);
            e2[row0 + r] = expf(s2);
            e3[row0 + r] = expf(s3);
        }
    }
}

// --- everything after k_rows, fused into ONE cooperative kernel -------------
// 256 wgs x 256 threads = 65536 threads, one element per thread. Phases
// separated by grid.sync(); all floating-point accumulation trees are
// bitwise-identical to the previously-verified separate kernels.
//
// p0: zero hist + out            p1: histogram(ranking) via atomics
// p2a: per-block hist slice sums p2b: exclusive scan -> histScan
// p3: scatter (r,idx,e2,e3) into bucket slots (atomic reserve)
// p4: exact rank within bucket -> sorted se2/se3
// p5: per-chunk sums             p6: prefix-scan + logf + atomic out
__global__ __launch_bounds__(256) void k_tail(
    const float* __restrict__ rk, const float* __restrict__ e2,
    const float* __restrict__ e3, unsigned* __restrict__ hist,
    unsigned* __restrict__ histScan, float4* __restrict__ sq,
    float* __restrict__ se2, float* __restrict__ se3,
    float* __restrict__ chunk2, float* __restrict__ chunk3,
    unsigned* __restrict__ bsum, float* __restrict__ out)
{
    cg::grid_group grid = cg::this_grid();
    const int t    = threadIdx.x;
    const int lane = t & 63;
    const int wid  = t >> 6;
    const int b    = (int)blockIdx.x;
    const int g    = b * 256 + t;

    __shared__ unsigned bs_s[4];
    __shared__ unsigned base_s[4], wsc[4];
    __shared__ float a2[4], a3[4];
    __shared__ float lt2s[4], lt3s[4], all2s[4], all3s[4], w2[4], w3[4];
    __shared__ double dsum[4];

    // --- p0: zero hist (1 bin/thread) + out -------------------------------
    hist[g] = 0u;
    if (g == 0) out[0] = 0.f;  // d_out is poisoned each call
    grid.sync();

    // --- p1: ranking histogram --------------------------------------------
    const float r = rk[g];
    const unsigned bk = bucket_of(r);
    atomicAdd(&hist[bk], 1u);
    grid.sync();

    // --- p2a: per-block sums of this block's 256-bin slice ----------------
    const unsigned h = hist[g];
    unsigned hs = h;
#pragma unroll
    for (int o = 32; o > 0; o >>= 1) hs += __shfl_xor(hs, o);
    if (lane == 0) bs_s[wid] = hs;
    __syncthreads();
    if (t == 0) bsum[b] = bs_s[0] + bs_s[1] + bs_s[2] + bs_s[3];
    grid.sync();

    // --- p2b: exclusive scan of hist -> histScan --------------------------
    unsigned pre = (t < b) ? bsum[t] : 0u;
#pragma unroll
    for (int o = 32; o > 0; o >>= 1) pre += __shfl_xor(pre, o);
    if (lane == 0) base_s[wid] = pre;
    unsigned inc = h;
#pragma unroll
    for (int o = 1; o < 64; o <<= 1) {
        unsigned n = __shfl_up(inc, o);
        if (lane >= o) inc += n;
    }
    if (lane == 63) wsc[wid] = inc;
    __syncthreads();
    unsigned base = base_s[0] + base_s[1] + base_s[2] + base_s[3];
    for (int k = 0; k < wid; ++k) base += wsc[k];
    histScan[g] = base + inc - h;  // exclusive start of bin g
    grid.sync();

    // --- p3: scatter packed (r, idx, e2, e3) into bucket slots ------------
    // Reserve via atomicAdd on histScan: afterwards histScan[b] = end_b.
    const float ve2 = e2[g];
    const float ve3 = e3[g];
    const unsigned slot = atomicAdd(&histScan[bk], 1u);
    sq[slot] = make_float4(r, __int_as_float(g), ve2, ve3);
    grid.sync();

    // --- p4: exact rank within bucket -> sorted scatter -------------------
    // Tie-break: higher original index first (matches reversed stable
    // descending argsort).
    const unsigned start = bk ? histScan[bk - 1] : 0u;
    const unsigned end   = histScan[bk];
    unsigned rankpos = start;
    for (unsigned m = start; m < end; ++m) {
        const float4 o = sq[m];
        if (o.x < r || (o.x == r && __float_as_int(o.y) > g)) rankpos++;
    }
    se2[rankpos] = ve2;
    se3[rankpos] = ve3;
    grid.sync();

    // --- p5: per-chunk (256-elem) sums of sorted e; keep own value --------
    const float v2 = se2[g];
    const float v3 = se3[g];
    float s2r = v2, s3r = v3;
#pragma unroll
    for (int o = 32; o > 0; o >>= 1) {
        s2r += __shfl_down(s2r, o);
        s3r += __shfl_down(s3r, o);
    }
    if (lane == 0) { a2[wid] = s2r; a3[wid] = s3r; }
    __syncthreads();
    if (t == 0) {
        chunk2[b] = a2[0] + a2[1] + a2[2] + a2[3];
        chunk3[b] = a3[0] + a3[1] + a3[2] + a3[3];
    }
    grid.sync();

    // --- p6: per-block scan + logf + atomic -------------------------------
    const float c2 = chunk2[t];
    const float c3 = chunk3[t];
    float lt2 = (t < b) ? c2 : 0.f, lt3 = (t < b) ? c3 : 0.f;
    float al2 = c2, al3 = c3;
#pragma unroll
    for (int o = 32; o > 0; o >>= 1) {
        lt2 += __shfl_xor(lt2, o);
        lt3 += __shfl_xor(lt3, o);
        al2 += __shfl_xor(al2, o);
        al3 += __shfl_xor(al3, o);
    }
    if (lane == 0) { lt2s[wid] = lt2; lt3s[wid] = lt3; all2s[wid] = al2; all3s[wid] = al3; }
    // inclusive wave scan of this block's 256 sorted values (kept in regs)
    float p2 = v2;
    float p3 = v3;
#pragma unroll
    for (int o = 1; o < 64; o <<= 1) {
        float n2 = __shfl_up(p2, o);
        float n3 = __shfl_up(p3, o);
        if (lane >= o) { p2 += n2; p3 += n3; }
    }
    if (lane == 63) { w2[wid] = p2; w3[wid] = p3; }
    __syncthreads();
    float base2 = lt2s[0] + lt2s[1] + lt2s[2] + lt2s[3];
    float base3 = lt3s[0] + lt3s[1] + lt3s[2] + lt3s[3];
    for (int w = 0; w < wid; ++w) { base2 += w2[w]; base3 += w3[w]; }
    double term = 0.0;
    if (g < NROWS - 1) {  // prefix lengths 1..N-1 only
        term = (double)logf(base2 + p2) + (double)logf(base3 + p3);
    }
#pragma unroll
    for (int o = 32; o > 0; o >>= 1) term += __shfl_down(term, o);
    if (lane == 0) dsum[wid] = term;
    __syncthreads();
    if (t == 0) {
        double contrib = -(dsum[0] + dsum[1] + dsum[2] + dsum[3]);
        if (b == 255) {
            const float T2 = all2s[0] + all2s[1] + all2s[2] + all2s[3];
            const float T3 = all3s[0] + all3s[1] + all3s[2] + all3s[3];
            contrib += (double)(NROWS - 1) * ((double)logf(T2) + (double)logf(T3));
        }
        atomicAdd(out, (float)contrib);
    }
}

extern "C" void kernel_launch(void* const* d_in, const int* in_sizes, int n_in,
                              void* d_out, int out_size, void* d_ws, size_t ws_size,
                              hipStream_t stream) {
    const float* x  = (const float*)d_in[0];  // [N, D]
    const float* b2 = (const float*)d_in[1];  // [1, D]
    const float* b3 = (const float*)d_in[2];  // [1, D]
    const float* rk = (const float*)d_in[3];  // [N]

    // Workspace layout (4-byte units).
    unsigned* hist     = (unsigned*)d_ws;            // N
    unsigned* histScan = hist + NROWS;               // N
    float4*   sq   = (float4*)(histScan + NROWS);    // 4N (offset 512KB, 16B-aligned)
    float*    e2   = (float*)(sq + NROWS);           // N
    float*    e3   = e2 + NROWS;                     // N
    float*    se2  = e3 + NROWS;                     // N
    float*    se3  = se2 + NROWS;                    // N
    float*    chunk2 = se3 + NROWS;                  // 256
    float*    chunk3 = chunk2 + 256;                 // 256
    unsigned* bsum   = (unsigned*)(chunk3 + 256);    // 256
    float*    outp   = (float*)d_out;

    k_rows<<<NROWS / 16, 256, 0, stream>>>(x, b2, b3, e2, e3);

    void* args[] = {
        (void*)&rk, (void*)&e2, (void*)&e3, (void*)&hist, (void*)&histScan,
        (void*)&sq, (void*)&se2, (void*)&se3, (void*)&chunk2, (void*)&chunk3,
        (void*)&bsum, (void*)&outp
    };
    hipLaunchCooperativeKernel((const void*)k_tail, dim3(256), dim3(256),
                               args, 0, stream);
}

// Round 3
// 237.432 us; speedup vs baseline: 1.6823x; 1.6823x over previous
//
#include <hip/hip_runtime.h>
#include <math.h>

// Problem constants (fixed by setup_inputs): N=65536 rows, D=512, out = 1 float.
#define NROWS 65536
#define DIM   512

typedef float f4 __attribute__((ext_vector_type(4)));

__device__ __forceinline__ unsigned bucket_of(float r) {
    // r in [0,1); mult by 2^16 is exact (exponent shift) -> monotone bucketing.
    unsigned b = (unsigned)(r * 65536.0f);
    return b > 65535u ? 65535u : b;
}

// --- per-row cosine sims -> e2/e3 -------------------------------------------
// 4 rows per wave: b2/b3 fragments + norms live in registers once per wave,
// 8 outstanding 16B non-temporal x-loads per lane. Arithmetic trees identical
// to the verified version (bitwise-same e2/e3).
__global__ __launch_bounds__(256) void k_rows(
    const float* __restrict__ x, const float* __restrict__ b2,
    const float* __restrict__ b3,
    float* __restrict__ e2, float* __restrict__ e3)
{
    const int wv   = (int)((blockIdx.x * 256u + threadIdx.x) >> 6);
    const int lane = threadIdx.x & 63;
    const int row0 = wv << 2;  // 4 rows per wave

    const f4* b2v = (const f4*)b2;
    const f4* b3v = (const f4*)b3;
    const f4 u0 = b2v[lane], u1 = b2v[lane + 64];
    const f4 w0 = b3v[lane], w1 = b3v[lane + 64];

    // ||b2||, ||b3|| once per wave
    float sb2 = 0.f, sb3 = 0.f;
    sb2 += u0.x * u0.x + u0.y * u0.y + u0.z * u0.z + u0.w * u0.w;
    sb2 += u1.x * u1.x + u1.y * u1.y + u1.z * u1.z + u1.w * u1.w;
    sb3 += w0.x * w0.x + w0.y * w0.y + w0.z * w0.z + w0.w * w0.w;
    sb3 += w1.x * w1.x + w1.y * w1.y + w1.z * w1.z + w1.w * w1.w;
#pragma unroll
    for (int off = 32; off > 0; off >>= 1) {
        sb2 += __shfl_xor(sb2, off);
        sb3 += __shfl_xor(sb3, off);
    }
    const float nb2 = sqrtf(sb2);
    const float nb3 = sqrtf(sb3);

    const f4* xr = (const f4*)(x + (size_t)row0 * DIM);
    f4 xv[4][2];
#pragma unroll
    for (int r = 0; r < 4; ++r) {
#pragma unroll
        for (int k = 0; k < 2; ++k)
            xv[r][k] = __builtin_nontemporal_load(&xr[r * 128 + lane + (k << 6)]);
    }

#pragma unroll
    for (int r = 0; r < 4; ++r) {
        float dot2 = 0.f, dot3 = 0.f, ss = 0.f;
        dot2 += xv[r][0].x * u0.x + xv[r][0].y * u0.y + xv[r][0].z * u0.z + xv[r][0].w * u0.w;
        dot2 += xv[r][1].x * u1.x + xv[r][1].y * u1.y + xv[r][1].z * u1.z + xv[r][1].w * u1.w;
        dot3 += xv[r][0].x * w0.x + xv[r][0].y * w0.y + xv[r][0].z * w0.z + xv[r][0].w * w0.w;
        dot3 += xv[r][1].x * w1.x + xv[r][1].y * w1.y + xv[r][1].z * w1.z + xv[r][1].w * w1.w;
        ss   += xv[r][0].x * xv[r][0].x + xv[r][0].y * xv[r][0].y + xv[r][0].z * xv[r][0].z + xv[r][0].w * xv[r][0].w;
        ss   += xv[r][1].x * xv[r][1].x + xv[r][1].y * xv[r][1].y + xv[r][1].z * xv[r][1].z + xv[r][1].w * xv[r][1].w;
#pragma unroll
        for (int off = 32; off > 0; off >>= 1) {
            dot2 += __shfl_xor(dot2, off);
            dot3 += __shfl_xor(dot3, off);
            ss   += __shfl_xor(ss, off);
        }
        if (lane == 0) {
            const float nx = sqrtf(ss);
            const float s2 = dot2 / fmaxf(nx * nb2, 1e-8f);
            const float s3 = dot3 / fmaxf(nx * nb3, 1e-8f);
            e2[row0 + r] = expf(s2);
            e3[row0 + r] = expf(s3);
        }
    }
}

// --- self-contained histogram + exclusive scan (replaces memset + hist ------
// atomics + bsum + histscan). Block b owns bins [256b, 256b+256). It scans
// ALL of rk (256KB, L2-resident; 64MB aggregate over 256 blocks ~ 2us at L2
// BW), counts keys below its range (-> scan base, no cross-block comms) and
// histograms keys inside its range into LDS. All-integer => exact.
__global__ __launch_bounds__(256) void k_histscan(const float* __restrict__ rk,
                                                  unsigned* __restrict__ histScan) {
    __shared__ unsigned lhist[256];
    __shared__ unsigned base_s[4], wsc[4];
    const int t = threadIdx.x, lane = t & 63, wid = t >> 6;
    const unsigned lo = (unsigned)blockIdx.x << 8;  // first owned bin
    lhist[t] = 0u;
    __syncthreads();

    const f4* rv = (const f4*)rk;
    unsigned pre = 0;  // #keys with bucket < lo
    for (int i = t; i < NROWS / 4; i += 256) {
        const f4 v = rv[i];
        unsigned bk;
        bk = bucket_of(v.x); pre += (bk < lo); if (bk - lo < 256u) atomicAdd(&lhist[bk - lo], 1u);
        bk = bucket_of(v.y); pre += (bk < lo); if (bk - lo < 256u) atomicAdd(&lhist[bk - lo], 1u);
        bk = bucket_of(v.z); pre += (bk < lo); if (bk - lo < 256u) atomicAdd(&lhist[bk - lo], 1u);
        bk = bucket_of(v.w); pre += (bk < lo); if (bk - lo < 256u) atomicAdd(&lhist[bk - lo], 1u);
    }
#pragma unroll
    for (int o = 32; o > 0; o >>= 1) pre += __shfl_xor(pre, o);
    if (lane == 0) base_s[wid] = pre;
    __syncthreads();  // lhist atomics + base_s visible

    const unsigned h = lhist[t];
    unsigned inc = h;
#pragma unroll
    for (int o = 1; o < 64; o <<= 1) {
        unsigned n = __shfl_up(inc, o);
        if (lane >= o) inc += n;
    }
    if (lane == 63) wsc[wid] = inc;
    __syncthreads();
    unsigned base = base_s[0] + base_s[1] + base_s[2] + base_s[3];
    for (int k = 0; k < wid; ++k) base += wsc[k];
    histScan[lo + t] = base + inc - h;  // exclusive start of bin
}

// --- scatter packed (r, idx, e2, e3) records into bucket slots --------------
// Reserves via atomicAdd on histScan itself: afterwards histScan[b] = end_b.
__global__ __launch_bounds__(256) void k_scatter(const float* __restrict__ ranking,
                                                 const float* __restrict__ e2,
                                                 const float* __restrict__ e3,
                                                 unsigned* __restrict__ histScan,
                                                 float4* __restrict__ sq) {
    const int i = (int)(blockIdx.x * 256u + threadIdx.x);
    const float r = ranking[i];
    const unsigned b = bucket_of(r);
    const unsigned slot = atomicAdd(&histScan[b], 1u);
    sq[slot] = make_float4(r, __int_as_float(i), e2[i], e3[i]);
}

// --- exact rank within bucket (packed records), scatter e into sorted order -
// Post-scatter histScan[b] = end_b; start_b = histScan[b-1] (0 for b==0).
// Tie-break: higher original index first (matches reversed stable descending argsort).
__global__ __launch_bounds__(256) void k_rank(const float4* __restrict__ sq,
                                              const unsigned* __restrict__ histScan,
                                              float* __restrict__ se2,
                                              float* __restrict__ se3) {
    const int s = (int)(blockIdx.x * 256u + threadIdx.x);
    const float4 me = sq[s];
    const float r = me.x;
    const int   i = __float_as_int(me.y);
    const unsigned b = bucket_of(r);
    const unsigned start = b ? histScan[b - 1] : 0u;
    const unsigned end   = histScan[b];
    unsigned rank = start;
    for (unsigned m = start; m < end; ++m) {
        const float4 o = sq[m];
        const float rj = o.x;
        const int   j  = __float_as_int(o.y);
        if (rj < r || (rj == r && j > i)) rank++;
    }
    se2[rank] = me.z;
    se3[rank] = me.w;
}

// --- per-chunk (256-elem) sums of sorted e; also zero-init out --------------
__global__ __launch_bounds__(256) void k_chunksum(const float* __restrict__ se2,
                                                  const float* __restrict__ se3,
                                                  float* __restrict__ chunk2,
                                                  float* __restrict__ chunk3,
                                                  float* __restrict__ out) {
    __shared__ float a2[4], a3[4];
    const int t = threadIdx.x;
    const int g = (int)(blockIdx.x * 256u + t);
    float v2 = se2[g];
    float v3 = se3[g];
#pragma unroll
    for (int o = 32; o > 0; o >>= 1) {
        v2 += __shfl_down(v2, o);
        v3 += __shfl_down(v3, o);
    }
    const int lane = t & 63, wid = t >> 6;
    if (lane == 0) { a2[wid] = v2; a3[wid] = v3; }
    __syncthreads();
    if (t == 0) {
        chunk2[blockIdx.x] = a2[0] + a2[1] + a2[2] + a2[3];
        chunk3[blockIdx.x] = a3[0] + a3[1] + a3[2] + a3[3];
        if (blockIdx.x == 0) out[0] = 0.f;  // d_out is poisoned each call
    }
}

// --- final: per-block scan + logf + atomic; block computes its own base by --
// reducing the chunk sums below it; block 255 adds (N-1)*log(total).
__global__ __launch_bounds__(256) void k_logsum(const float* __restrict__ se2,
                                                const float* __restrict__ se3,
                                                const float* __restrict__ chunk2,
                                                const float* __restrict__ chunk3,
                                                float* __restrict__ out) {
    __shared__ float lt2s[4], lt3s[4], all2s[4], all3s[4], w2[4], w3[4];
    __shared__ double dsum[4];
    const int t    = threadIdx.x;
    const int lane = t & 63;
    const int wid  = t >> 6;
    const int b    = (int)blockIdx.x;
    const int g    = b * 256 + t;
    // chunk-sum prefixes (exclusive of own chunk) and totals
    const float c2 = chunk2[t];
    const float c3 = chunk3[t];
    float lt2 = (t < b) ? c2 : 0.f, lt3 = (t < b) ? c3 : 0.f;
    float al2 = c2, al3 = c3;
#pragma unroll
    for (int o = 32; o > 0; o >>= 1) {
        lt2 += __shfl_xor(lt2, o);
        lt3 += __shfl_xor(lt3, o);
        al2 += __shfl_xor(al2, o);
        al3 += __shfl_xor(al3, o);
    }
    if (lane == 0) { lt2s[wid] = lt2; lt3s[wid] = lt3; all2s[wid] = al2; all3s[wid] = al3; }
    // inclusive wave scan of this block's 256 sorted values
    float p2 = se2[g];
    float p3 = se3[g];
#pragma unroll
    for (int o = 1; o < 64; o <<= 1) {
        float n2 = __shfl_up(p2, o);
        float n3 = __shfl_up(p3, o);
        if (lane >= o) { p2 += n2; p3 += n3; }
    }
    if (lane == 63) { w2[wid] = p2; w3[wid] = p3; }
    __syncthreads();
    float base2 = lt2s[0] + lt2s[1] + lt2s[2] + lt2s[3];
    float base3 = lt3s[0] + lt3s[1] + lt3s[2] + lt3s[3];
    for (int w = 0; w < wid; ++w) { base2 += w2[w]; base3 += w3[w]; }
    double term = 0.0;
    if (g < NROWS - 1) {  // prefix lengths 1..N-1 only
        term = (double)logf(base2 + p2) + (double)logf(base3 + p3);
    }
#pragma unroll
    for (int o = 32; o > 0; o >>= 1) term += __shfl_down(term, o);
    if (lane == 0) dsum[wid] = term;
    __syncthreads();
    if (t == 0) {
        double contrib = -(dsum[0] + dsum[1] + dsum[2] + dsum[3]);
        if (b == 255) {
            const float T2 = all2s[0] + all2s[1] + all2s[2] + all2s[3];
            const float T3 = all3s[0] + all3s[1] + all3s[2] + all3s[3];
            contrib += (double)(NROWS - 1) * ((double)logf(T2) + (double)logf(T3));
        }
        atomicAdd(out, (float)contrib);
    }
}

extern "C" void kernel_launch(void* const* d_in, const int* in_sizes, int n_in,
                              void* d_out, int out_size, void* d_ws, size_t ws_size,
                              hipStream_t stream) {
    const float* x  = (const float*)d_in[0];  // [N, D]
    const float* b2 = (const float*)d_in[1];  // [1, D]
    const float* b3 = (const float*)d_in[2];  // [1, D]
    const float* rk = (const float*)d_in[3];  // [N]

    // Workspace layout (4-byte units). (hist slot kept for layout stability,
    // no longer used.)
    unsigned* hist     = (unsigned*)d_ws;            // N (unused)
    unsigned* histScan = hist + NROWS;               // N
    float4*   sq   = (float4*)(histScan + NROWS);    // 4N (offset 512KB, 16B-aligned)
    float*    e2   = (float*)(sq + NROWS);           // N
    float*    e3   = e2 + NROWS;                     // N
    float*    se2  = e3 + NROWS;                     // N
    float*    se3  = se2 + NROWS;                    // N
    float*    chunk2 = se3 + NROWS;                  // 256
    float*    chunk3 = chunk2 + 256;                 // 256

    k_rows<<<NROWS / 16, 256, 0, stream>>>(x, b2, b3, e2, e3);
    k_histscan<<<256, 256, 0, stream>>>(rk, histScan);
    k_scatter<<<NROWS / 256, 256, 0, stream>>>(rk, e2, e3, histScan, sq);
    k_rank<<<NROWS / 256, 256, 0, stream>>>(sq, histScan, se2, se3);
    k_chunksum<<<NROWS / 256, 256, 0, stream>>>(se2, se3, chunk2, chunk3, (float*)d_out);
    k_logsum<<<NROWS / 256, 256, 0, stream>>>(se2, se3, chunk2, chunk3, (float*)d_out);
}

// Round 5
// 210.491 us; speedup vs baseline: 1.8976x; 1.1280x over previous
//
#include <hip/hip_runtime.h>
#include <math.h>

// Problem constants (fixed by setup_inputs): N=65536 rows, D=512, out = 1 float.
#define NROWS 65536
#define DIM   512

typedef float f4 __attribute__((ext_vector_type(4)));

__device__ __forceinline__ unsigned bucket_of(float r) {
    // r in [0,1); mult by 2^16 is exact (exponent shift) -> monotone bucketing.
    unsigned b = (unsigned)(r * 65536.0f);
    return b > 65535u ? 65535u : b;
}

// --- per-row cosine sims -> e2/e3, fused b-norms + ranking histogram --------
// 4 rows per wave: b2/b3 fragments + norms live in registers once per wave,
// 8 outstanding 16B non-temporal x-loads per lane, 3 shuffle-reduce trees per
// row instead of 5. Float accumulation trees bitwise-identical to the
// verified round-0 kernel.
__global__ __launch_bounds__(256) void k_rows(
    const float* __restrict__ x, const float* __restrict__ b2,
    const float* __restrict__ b3, const float* __restrict__ ranking,
    float* __restrict__ e2, float* __restrict__ e3,
    unsigned* __restrict__ hist)
{
    const int wv   = (int)((blockIdx.x * 256u + threadIdx.x) >> 6);
    const int lane = threadIdx.x & 63;
    const int row0 = wv << 2;  // 4 rows per wave

    const f4* b2v = (const f4*)b2;
    const f4* b3v = (const f4*)b3;
    const f4 u0 = b2v[lane], u1 = b2v[lane + 64];
    const f4 w0 = b3v[lane], w1 = b3v[lane + 64];

    // ||b2||, ||b3|| once per wave
    float sb2 = 0.f, sb3 = 0.f;
    sb2 += u0.x * u0.x + u0.y * u0.y + u0.z * u0.z + u0.w * u0.w;
    sb2 += u1.x * u1.x + u1.y * u1.y + u1.z * u1.z + u1.w * u1.w;
    sb3 += w0.x * w0.x + w0.y * w0.y + w0.z * w0.z + w0.w * w0.w;
    sb3 += w1.x * w1.x + w1.y * w1.y + w1.z * w1.z + w1.w * w1.w;
#pragma unroll
    for (int off = 32; off > 0; off >>= 1) {
        sb2 += __shfl_xor(sb2, off);
        sb3 += __shfl_xor(sb3, off);
    }
    const float nb2 = sqrtf(sb2);
    const float nb3 = sqrtf(sb3);

    const f4* xr = (const f4*)(x + (size_t)row0 * DIM);
    f4 xv[4][2];
#pragma unroll
    for (int r = 0; r < 4; ++r) {
#pragma unroll
        for (int k = 0; k < 2; ++k)
            xv[r][k] = __builtin_nontemporal_load(&xr[r * 128 + lane + (k << 6)]);
    }

#pragma unroll
    for (int r = 0; r < 4; ++r) {
        float dot2 = 0.f, dot3 = 0.f, ss = 0.f;
        dot2 += xv[r][0].x * u0.x + xv[r][0].y * u0.y + xv[r][0].z * u0.z + xv[r][0].w * u0.w;
        dot2 += xv[r][1].x * u1.x + xv[r][1].y * u1.y + xv[r][1].z * u1.z + xv[r][1].w * u1.w;
        dot3 += xv[r][0].x * w0.x + xv[r][0].y * w0.y + xv[r][0].z * w0.z + xv[r][0].w * w0.w;
        dot3 += xv[r][1].x * w1.x + xv[r][1].y * w1.y + xv[r][1].z * w1.z + xv[r][1].w * w1.w;
        ss   += xv[r][0].x * xv[r][0].x + xv[r][0].y * xv[r][0].y + xv[r][0].z * xv[r][0].z + xv[r][0].w * xv[r][0].w;
        ss   += xv[r][1].x * xv[r][1].x + xv[r][1].y * xv[r][1].y + xv[r][1].z * xv[r][1].z + xv[r][1].w * xv[r][1].w;
#pragma unroll
        for (int off = 32; off > 0; off >>= 1) {
            dot2 += __shfl_xor(dot2, off);
            dot3 += __shfl_xor(dot3, off);
            ss   += __shfl_xor(ss, off);
        }
        if (lane == 0) {
            const float nx = sqrtf(ss);
            const float s2 = dot2 / fmaxf(nx * nb2, 1e-8f);
            const float s3 = dot3 / fmaxf(nx * nb3, 1e-8f);
            e2[row0 + r] = expf(s2);
            e3[row0 + r] = expf(s3);
        }
    }
    if (lane < 4) {
        atomicAdd(&hist[bucket_of(ranking[row0 + lane])], 1u);
    }
}

// --- per-block (256-bin) sums of histogram, coalesced -----------------------
__global__ __launch_bounds__(256) void k_bsum(const unsigned* __restrict__ hist,
                                              unsigned* __restrict__ bsum) {
    const int t = threadIdx.x;
    unsigned v = hist[blockIdx.x * 256u + t];
#pragma unroll
    for (int o = 32; o > 0; o >>= 1) v += __shfl_xor(v, o);
    __shared__ unsigned a[4];
    if ((t & 63) == 0) a[t >> 6] = v;
    __syncthreads();
    if (t == 0) bsum[blockIdx.x] = a[0] + a[1] + a[2] + a[3];
}

// --- exclusive scan of histogram: block b scans its 256 bins + redundant ----
// reduction of the <=256 block partials below it (L2-hot, trivial).
__global__ __launch_bounds__(256) void k_histscan(const unsigned* __restrict__ hist,
                                                  const unsigned* __restrict__ bsum,
                                                  unsigned* __restrict__ histScan) {
    const int t = threadIdx.x, lane = t & 63, wid = t >> 6;
    const int b = (int)blockIdx.x;
    __shared__ unsigned base_s[4], w[4];
    unsigned pre = (t < b) ? bsum[t] : 0u;
#pragma unroll
    for (int o = 32; o > 0; o >>= 1) pre += __shfl_xor(pre, o);
    if (lane == 0) base_s[wid] = pre;
    const unsigned h = hist[b * 256u + t];
    unsigned inc = h;
#pragma unroll
    for (int o = 1; o < 64; o <<= 1) {
        unsigned n = __shfl_up(inc, o);
        if (lane >= o) inc += n;
    }
    if (lane == 63) w[wid] = inc;
    __syncthreads();
    unsigned base = base_s[0] + base_s[1] + base_s[2] + base_s[3];
    for (int k = 0; k < wid; ++k) base += w[k];
    histScan[b * 256u + t] = base + inc - h;  // exclusive start of bin
}

// --- scatter packed (r, idx, e2, e3) records into bucket slots --------------
// Reserves via atomicAdd on histScan itself: afterwards histScan[b] = end_b.
__global__ __launch_bounds__(256) void k_scatter(const float* __restrict__ ranking,
                                                 const float* __restrict__ e2,
                                                 const float* __restrict__ e3,
                                                 unsigned* __restrict__ histScan,
                                                 float4* __restrict__ sq) {
    const int i = (int)(blockIdx.x * 256u + threadIdx.x);
    const float r = ranking[i];
    const unsigned b = bucket_of(r);
    const unsigned slot = atomicAdd(&histScan[b], 1u);
    sq[slot] = make_float4(r, __int_as_float(i), e2[i], e3[i]);
}

// --- exact rank within bucket (packed records), scatter e into sorted order -
// Post-scatter histScan[b] = end_b; start_b = histScan[b-1] (0 for b==0).
// Tie-break: higher original index first (matches reversed stable descending argsort).
__global__ __launch_bounds__(256) void k_rank(const float4* __restrict__ sq,
                                              const unsigned* __restrict__ histScan,
                                              float* __restrict__ se2,
                                              float* __restrict__ se3) {
    const int s = (int)(blockIdx.x * 256u + threadIdx.x);
    const float4 me = sq[s];
    const float r = me.x;
    const int   i = __float_as_int(me.y);
    const unsigned b = bucket_of(r);
    const unsigned start = b ? histScan[b - 1] : 0u;
    const unsigned end   = histScan[b];
    unsigned rank = start;
    for (unsigned m = start; m < end; ++m) {
        const float4 o = sq[m];
        const float rj = o.x;
        const int   j  = __float_as_int(o.y);
        if (rj < r || (rj == r && j > i)) rank++;
    }
    se2[rank] = me.z;
    se3[rank] = me.w;
}

// --- per-chunk (256-elem) sums of sorted e; also zero-init out --------------
__global__ __launch_bounds__(256) void k_chunksum(const float* __restrict__ se2,
                                                  const float* __restrict__ se3,
                                                  float* __restrict__ chunk2,
                                                  float* __restrict__ chunk3,
                                                  float* __restrict__ out) {
    __shared__ float a2[4], a3[4];
    const int t = threadIdx.x;
    const int g = (int)(blockIdx.x * 256u + t);
    float v2 = se2[g];
    float v3 = se3[g];
#pragma unroll
    for (int o = 32; o > 0; o >>= 1) {
        v2 += __shfl_down(v2, o);
        v3 += __shfl_down(v3, o);
    }
    const int lane = t & 63, wid = t >> 6;
    if (lane == 0) { a2[wid] = v2; a3[wid] = v3; }
    __syncthreads();
    if (t == 0) {
        chunk2[blockIdx.x] = a2[0] + a2[1] + a2[2] + a2[3];
        chunk3[blockIdx.x] = a3[0] + a3[1] + a3[2] + a3[3];
        if (blockIdx.x == 0) out[0] = 0.f;  // d_out is poisoned each call
    }
}

// --- final: per-block scan + logf + atomic; block computes its own base by --
// reducing the chunk sums below it; block 255 adds (N-1)*log(total).
__global__ __launch_bounds__(256) void k_logsum(const float* __restrict__ se2,
                                                const float* __restrict__ se3,
                                                const float* __restrict__ chunk2,
                                                const float* __restrict__ chunk3,
                                                float* __restrict__ out) {
    __shared__ float lt2s[4], lt3s[4], all2s[4], all3s[4], w2[4], w3[4];
    __shared__ double dsum[4];
    const int t    = threadIdx.x;
    const int lane = t & 63;
    const int wid  = t >> 6;
    const int b    = (int)blockIdx.x;
    const int g    = b * 256 + t;
    // chunk-sum prefixes (exclusive of own chunk) and totals
    const float c2 = chunk2[t];
    const float c3 = chunk3[t];
    float lt2 = (t < b) ? c2 : 0.f, lt3 = (t < b) ? c3 : 0.f;
    float al2 = c2, al3 = c3;
#pragma unroll
    for (int o = 32; o > 0; o >>= 1) {
        lt2 += __shfl_xor(lt2, o);
        lt3 += __shfl_xor(lt3, o);
        al2 += __shfl_xor(al2, o);
        al3 += __shfl_xor(al3, o);
    }
    if (lane == 0) { lt2s[wid] = lt2; lt3s[wid] = lt3; all2s[wid] = al2; all3s[wid] = al3; }
    // inclusive wave scan of this block's 256 sorted values
    float p2 = se2[g];
    float p3 = se3[g];
#pragma unroll
    for (int o = 1; o < 64; o <<= 1) {
        float n2 = __shfl_up(p2, o);
        float n3 = __shfl_up(p3, o);
        if (lane >= o) { p2 += n2; p3 += n3; }
    }
    if (lane == 63) { w2[wid] = p2; w3[wid] = p3; }
    __syncthreads();
    float base2 = lt2s[0] + lt2s[1] + lt2s[2] + lt2s[3];
    float base3 = lt3s[0] + lt3s[1] + lt3s[2] + lt3s[3];
    for (int w = 0; w < wid; ++w) { base2 += w2[w]; base3 += w3[w]; }
    double term = 0.0;
    if (g < NROWS - 1) {  // prefix lengths 1..N-1 only
        term = (double)logf(base2 + p2) + (double)logf(base3 + p3);
    }
#pragma unroll
    for (int o = 32; o > 0; o >>= 1) term += __shfl_down(term, o);
    if (lane == 0) dsum[wid] = term;
    __syncthreads();
    if (t == 0) {
        double contrib = -(dsum[0] + dsum[1] + dsum[2] + dsum[3]);
        if (b == 255) {
            const float T2 = all2s[0] + all2s[1] + all2s[2] + all2s[3];
            const float T3 = all3s[0] + all3s[1] + all3s[2] + all3s[3];
            contrib += (double)(NROWS - 1) * ((double)logf(T2) + (double)logf(T3));
        }
        atomicAdd(out, (float)contrib);
    }
}

extern "C" void kernel_launch(void* const* d_in, const int* in_sizes, int n_in,
                              void* d_out, int out_size, void* d_ws, size_t ws_size,
                              hipStream_t stream) {
    const float* x  = (const float*)d_in[0];  // [N, D]
    const float* b2 = (const float*)d_in[1];  // [1, D]
    const float* b3 = (const float*)d_in[2];  // [1, D]
    const float* rk = (const float*)d_in[3];  // [N]

    // Workspace layout (4-byte units).
    unsigned* hist     = (unsigned*)d_ws;            // N (must be zeroed)
    unsigned* histScan = hist + NROWS;               // N
    float4*   sq   = (float4*)(histScan + NROWS);    // 4N (offset 512KB, 16B-aligned)
    float*    e2   = (float*)(sq + NROWS);           // N
    float*    e3   = e2 + NROWS;                     // N
    float*    se2  = e3 + NROWS;                     // N
    float*    se3  = se2 + NROWS;                    // N
    float*    chunk2 = se3 + NROWS;                  // 256
    float*    chunk3 = chunk2 + 256;                 // 256
    unsigned* bsum   = (unsigned*)(chunk3 + 256);    // 256

    // hist must be zero each call (ws poisoned 0xAA).
    hipMemsetAsync(hist, 0, NROWS * sizeof(unsigned), stream);

    k_rows<<<NROWS / 16, 256, 0, stream>>>(x, b2, b3, rk, e2, e3, hist);
    k_bsum<<<256, 256, 0, stream>>>(hist, bsum);
    k_histscan<<<256, 256, 0, stream>>>(hist, bsum, histScan);
    k_scatter<<<NROWS / 256, 256, 0, stream>>>(rk, e2, e3, histScan, sq);
    k_rank<<<NROWS / 256, 256, 0, stream>>>(sq, histScan, se2, se3);
    k_chunksum<<<NROWS / 256, 256, 0, stream>>>(se2, se3, chunk2, chunk3, (float*)d_out);
    k_logsum<<<NROWS / 256, 256, 0, stream>>>(se2, se3, chunk2, chunk3, (float*)d_out);
}